// Round 9
// baseline (53.523 us; speedup 1.0000x reference)
//
#include <hip/hip_runtime.h>
#include <hip/hip_bf16.h>

// out[m,u] = sum_t x[m,t] * W_eff[u,t] + b_eff[u]      (m = 32*512 rows)
//   W_eff = Ws + (Wt - Ws) @ A   (A = causal window-mean, window 25)
// Round-9: round-8 skeleton (x-tile in LDS, W streamed global->reg with
// depth-1 reg pipeline, 1024 thr / 16 waves, 1 block/CU) + chunked x-staging:
// x columns staged in 3 chunks; chunk c+1's global loads are issued at the
// START of K-phase c and LDS-written at its END (T14 issue-early/write-late),
// hiding ~2/3 of the prologue under MFMA/W-stream work. 3 barriers total.

#define Tdim  720
#define KP    736      // padded K (23*32); Wb zero-filled for k>=720
#define WROWS 768      // padded u-rows of Wb (zero rows >=720)
#define NK    23
#define BM    64       // m-rows per block
#define APAD  744      // LDS row stride in elems (2-way bank alias, free per m136)

using bf16x8 = __attribute__((ext_vector_type(8))) __bf16;
using f32x4  = __attribute__((ext_vector_type(4))) float;

__global__ void fold_w_kernel(const float* __restrict__ tw,
                              const float* __restrict__ tb,
                              const float* __restrict__ sw,
                              const float* __restrict__ sb,
                              __bf16* __restrict__ Wb,
                              float* __restrict__ beff) {
  int idx = blockIdx.x * 256 + threadIdx.x;
  if (idx >= WROWS * KP) return;
  int u = idx / KP;
  int i = idx - u * KP;
  float w = 0.0f;
  if (u < Tdim && i < Tdim) {
    const float* twr = tw + (size_t)u * Tdim;
    const float* swr = sw + (size_t)u * Tdim;
    int tend = (i + 25 < Tdim) ? (i + 25) : Tdim;
    float acc = 0.0f;
    if (i >= 24) {
      #pragma unroll 5
      for (int t = i; t < tend; ++t) acc += twr[t] - swr[t];
      acc *= 0.04f;
    } else {
      for (int t = i; t < tend; ++t) {
        float c = (t >= 24) ? 0.04f : 1.0f / (float)(t + 1);
        acc += (twr[t] - swr[t]) * c;
      }
    }
    w = swr[i] + acc;
  }
  Wb[idx] = (__bf16)w;
  if (i == 0 && u < Tdim) beff[u] = tb[u] + sb[u];
}

__global__ __launch_bounds__(1024, 1)
void dlinear_gemm(const float* __restrict__ x,
                  const __bf16* __restrict__ Wb,
                  const float* __restrict__ beff,
                  float* __restrict__ out) {
  __shared__ __bf16 As[BM * APAD];   // 95232 B -> 1 block/CU

  const int tid  = threadIdx.x;
  const int lane = tid & 63;
  const int wid  = tid >> 6;          // 0..15
  const int lg = lane >> 4, lr = lane & 15;

  const int m0 = blockIdx.x * BM;
  const int u0 = wid * 48;            // wave owns 48 u-cols (768 = 16*48 padded)

  // ---- W stream pointers: frag ni -> row u0+ni*16+lr, 16B chunk lg within K-step
  const __bf16* wp[3];
  #pragma unroll
  for (int ni = 0; ni < 3; ++ni)
    wp[ni] = Wb + (size_t)(u0 + ni * 16 + lr) * KP + lg * 8;

  int arofs[4];
  #pragma unroll
  for (int mi = 0; mi < 4; ++mi) arofs[mi] = (mi * 16 + lr) * APAD + lg * 8;

  f32x4 acc[4][3];
  #pragma unroll
  for (int mi = 0; mi < 4; ++mi)
    #pragma unroll
    for (int ni = 0; ni < 3; ++ni) {
      f32x4 z; z[0] = 0.f; z[1] = 0.f; z[2] = 0.f; z[3] = 0.f;
      acc[mi][ni] = z;
    }

  bf16x8 bb[2][3];                    // depth-1 W pipeline (r8-proven)
  #pragma unroll
  for (int ni = 0; ni < 3; ++ni) bb[0][ni] = *(const bf16x8*)wp[ni];   // t=0

  // ---- stage chunk 0: cols [0,256)  (2048 units of 8 f32; 2 per thread)
  {
    const int unit0 = tid, unit1 = tid + 1024;
    const float* p0 = x + (size_t)(m0 + (unit0 >> 5)) * Tdim + (unit0 & 31) * 8;
    const float* p1 = x + (size_t)(m0 + (unit1 >> 5)) * Tdim + (unit1 & 31) * 8;
    f32x4 a0 = ((const f32x4*)p0)[0], a1 = ((const f32x4*)p0)[1];
    f32x4 a2 = ((const f32x4*)p1)[0], a3 = ((const f32x4*)p1)[1];
    bf16x8 v0, v1;
    #pragma unroll
    for (int j = 0; j < 4; ++j) {
      v0[j] = (__bf16)a0[j]; v0[j + 4] = (__bf16)a1[j];
      v1[j] = (__bf16)a2[j]; v1[j + 4] = (__bf16)a3[j];
    }
    *(bf16x8*)(&As[(unit0 >> 5) * APAD + (unit0 & 31) * 8]) = v0;
    *(bf16x8*)(&As[(unit1 >> 5) * APAD + (unit1 & 31) * 8]) = v1;
  }
  __syncthreads();

  // ================= phase 0: K-steps 0..7 (cols 0..255) =================
  // issue chunk-1 loads (cols 256..511) FIRST; LDS-write them at phase end.
  f32x4 c1a0, c1a1, c1b0, c1b1;
  {
    const int unit0 = tid, unit1 = tid + 1024;
    const float* p0 = x + (size_t)(m0 + (unit0 >> 5)) * Tdim + 256 + (unit0 & 31) * 8;
    const float* p1 = x + (size_t)(m0 + (unit1 >> 5)) * Tdim + 256 + (unit1 & 31) * 8;
    c1a0 = ((const f32x4*)p0)[0]; c1a1 = ((const f32x4*)p0)[1];
    c1b0 = ((const f32x4*)p1)[0]; c1b1 = ((const f32x4*)p1)[1];
  }
  #pragma unroll
  for (int t = 0; t < 8; ++t) {
    #pragma unroll
    for (int ni = 0; ni < 3; ++ni)
      bb[(t + 1) & 1][ni] = *(const bf16x8*)(wp[ni] + (t + 1) * 32);
    bf16x8 av[4];
    #pragma unroll
    for (int mi = 0; mi < 4; ++mi) av[mi] = *(const bf16x8*)(&As[arofs[mi] + t * 32]);
    #pragma unroll
    for (int mi = 0; mi < 4; ++mi)
      #pragma unroll
      for (int ni = 0; ni < 3; ++ni)
        acc[mi][ni] = __builtin_amdgcn_mfma_f32_16x16x32_bf16(av[mi], bb[t & 1][ni],
                                                              acc[mi][ni], 0, 0, 0);
  }
  {  // write chunk 1 to LDS (cols 256..511; disjoint from phase-0 reads)
    const int unit0 = tid, unit1 = tid + 1024;
    bf16x8 v0, v1;
    #pragma unroll
    for (int j = 0; j < 4; ++j) {
      v0[j] = (__bf16)c1a0[j]; v0[j + 4] = (__bf16)c1a1[j];
      v1[j] = (__bf16)c1b0[j]; v1[j + 4] = (__bf16)c1b1[j];
    }
    *(bf16x8*)(&As[(unit0 >> 5) * APAD + 256 + (unit0 & 31) * 8]) = v0;
    *(bf16x8*)(&As[(unit1 >> 5) * APAD + 256 + (unit1 & 31) * 8]) = v1;
  }
  __syncthreads();

  // ================= phase 1: K-steps 8..15 (cols 256..511) ==============
  // issue chunk-2 loads (cols 512..735; units with col8>=26 are pure pad ->
  // no load, zero write; 208 = 26*8 exactly, so no partial units, no OOB).
  f32x4 c2a0, c2a1, c2b0, c2b1;
  const int u2_0 = tid, u2_1 = tid + 1024;
  const int r20 = u2_0 / 28, c20 = u2_0 - r20 * 28;
  const int r21 = u2_1 / 28, c21 = u2_1 - r21 * 28;
  const bool v20 = (c20 < 26);
  const bool v21 = (u2_1 < 1792) && (c21 < 26);
  if (v20) {
    const float* p = x + (size_t)(m0 + r20) * Tdim + 512 + c20 * 8;
    c2a0 = ((const f32x4*)p)[0]; c2a1 = ((const f32x4*)p)[1];
  }
  if (v21) {
    const float* p = x + (size_t)(m0 + r21) * Tdim + 512 + c21 * 8;
    c2b0 = ((const f32x4*)p)[0]; c2b1 = ((const f32x4*)p)[1];
  }
  #pragma unroll
  for (int t = 8; t < 16; ++t) {
    #pragma unroll
    for (int ni = 0; ni < 3; ++ni)
      bb[(t + 1) & 1][ni] = *(const bf16x8*)(wp[ni] + (t + 1) * 32);
    bf16x8 av[4];
    #pragma unroll
    for (int mi = 0; mi < 4; ++mi) av[mi] = *(const bf16x8*)(&As[arofs[mi] + t * 32]);
    #pragma unroll
    for (int mi = 0; mi < 4; ++mi)
      #pragma unroll
      for (int ni = 0; ni < 3; ++ni)
        acc[mi][ni] = __builtin_amdgcn_mfma_f32_16x16x32_bf16(av[mi], bb[t & 1][ni],
                                                              acc[mi][ni], 0, 0, 0);
  }
  {  // write chunk 2 (cols 512..743 incl. zero pad)
    bf16x8 v0, v1;
    #pragma unroll
    for (int j = 0; j < 4; ++j) {
      v0[j] = v20 ? (__bf16)c2a0[j] : (__bf16)0.0f;
      v0[j + 4] = v20 ? (__bf16)c2a1[j] : (__bf16)0.0f;
      v1[j] = v21 ? (__bf16)c2b0[j] : (__bf16)0.0f;
      v1[j + 4] = v21 ? (__bf16)c2b1[j] : (__bf16)0.0f;
    }
    *(bf16x8*)(&As[r20 * APAD + 512 + c20 * 8]) = v0;
    if (u2_1 < 1792)
      *(bf16x8*)(&As[r21 * APAD + 512 + c21 * 8]) = v1;
  }
  __syncthreads();

  // ================= phase 2: K-steps 16..22 (cols 512..735) =============
  #pragma unroll
  for (int t = 16; t < 23; ++t) {
    if (t < 22) {
      #pragma unroll
      for (int ni = 0; ni < 3; ++ni)
        bb[(t + 1) & 1][ni] = *(const bf16x8*)(wp[ni] + (t + 1) * 32);
    }
    bf16x8 av[4];
    #pragma unroll
    for (int mi = 0; mi < 4; ++mi) av[mi] = *(const bf16x8*)(&As[arofs[mi] + t * 32]);
    #pragma unroll
    for (int mi = 0; mi < 4; ++mi)
      #pragma unroll
      for (int ni = 0; ni < 3; ++ni)
        acc[mi][ni] = __builtin_amdgcn_mfma_f32_16x16x32_bf16(av[mi], bb[t & 1][ni],
                                                              acc[mi][ni], 0, 0, 0);
  }

  // ---- epilogue: C/D layout col = lr -> u, row = lg*4 + j -> m
  #pragma unroll
  for (int ni = 0; ni < 3; ++ni) {
    const int u = u0 + ni * 16 + lr;
    if (u >= Tdim) continue;
    const float bias = beff[u];
    #pragma unroll
    for (int mi = 0; mi < 4; ++mi) {
      const int mb = m0 + mi * 16 + lg * 4;
      #pragma unroll
      for (int j = 0; j < 4; ++j)
        out[(size_t)(mb + j) * Tdim + u] = acc[mi][ni][j] + bias;
    }
  }
}

extern "C" void kernel_launch(void* const* d_in, const int* in_sizes, int n_in,
                              void* d_out, int out_size, void* d_ws, size_t ws_size,
                              hipStream_t stream) {
  const float* x  = (const float*)d_in[0];
  const float* tw = (const float*)d_in[1];
  const float* tb = (const float*)d_in[2];
  const float* sw = (const float*)d_in[3];
  const float* sb = (const float*)d_in[4];
  float* out = (float*)d_out;

  __bf16* Wb  = (__bf16*)d_ws;
  float* beff = (float*)((char*)d_ws + (size_t)WROWS * KP * sizeof(__bf16));

  const int fold_total = WROWS * KP;
  fold_w_kernel<<<dim3((fold_total + 255) / 256), dim3(256), 0, stream>>>(
      tw, tb, sw, sb, Wb, beff);

  const int M = in_sizes[0] / Tdim;            // 16384
  dim3 grid(M / BM);                           // 256 blocks, 1 per CU
  dlinear_gemm<<<grid, dim3(1024), 0, stream>>>(x, Wb, beff, out);
}